// Round 7
// baseline (153.423 us; speedup 1.0000x reference)
//
#include <hip/hip_runtime.h>
#include <stdint.h>

// Problem constants
#define BB 16
#define TT 4096
#define HH 64
#define MM 640     // HH*DD

// attn geometry
#define PAD4  41            // LDS row stride in float4 (656 B -> banks spread)
#define ROWSF (PAD4 * 4)    // 164 floats
#define QVOFF (16 * ROWSF)  // v tile base (floats)
#define NPART 16            // blocks per (b,hg)
#define NITER 16            // tiles per block: 256 t-tiles / NPART
#define NBLK  (64 * NPART)  // 1024 blocks

// ---------------------------------------------------------------------------
// Kernel 1: ksum[b][m] = sum_t key[b][t][m]  (~26 us, near read roofline)
// ---------------------------------------------------------------------------
__global__ void __launch_bounds__(256)
ksum_kernel(const float* __restrict__ key, float* __restrict__ ksum) {
    int g = blockIdx.x * blockDim.x + threadIdx.x;   // b*160 + c
    int b = g / 160;
    int c = g % 160;
    int t0 = blockIdx.y * 32;

    const float4* p = reinterpret_cast<const float4*>(key)
                    + (size_t)b * TT * 160 + (size_t)t0 * 160 + c;

    float4 a0 = make_float4(0.f,0.f,0.f,0.f);
    float4 a1 = make_float4(0.f,0.f,0.f,0.f);
    float4 a2 = make_float4(0.f,0.f,0.f,0.f);
    float4 a3 = make_float4(0.f,0.f,0.f,0.f);
    #pragma unroll
    for (int i = 0; i < 32; i += 4) {
        float4 x0 = p[(size_t)(i + 0) * 160];
        float4 x1 = p[(size_t)(i + 1) * 160];
        float4 x2 = p[(size_t)(i + 2) * 160];
        float4 x3 = p[(size_t)(i + 3) * 160];
        a0.x += x0.x; a0.y += x0.y; a0.z += x0.z; a0.w += x0.w;
        a1.x += x1.x; a1.y += x1.y; a1.z += x1.z; a1.w += x1.w;
        a2.x += x2.x; a2.y += x2.y; a2.z += x2.z; a2.w += x2.w;
        a3.x += x3.x; a3.y += x3.y; a3.z += x3.z; a3.w += x3.w;
    }
    float sx = (a0.x + a1.x) + (a2.x + a3.x);
    float sy = (a0.y + a1.y) + (a2.y + a3.y);
    float sz = (a0.z + a1.z) + (a2.z + a3.z);
    float sw = (a0.w + a1.w) + (a2.w + a3.w);

    float* dst = ksum + b * MM + c * 4;
    atomicAdd(dst + 0, sx);
    atomicAdd(dst + 1, sy);
    atomicAdd(dst + 2, sz);
    atomicAdd(dst + 3, sw);
}

// ---------------------------------------------------------------------------
// Robust tanh via rcp (exp of negative arg only -> never overflows)
// ---------------------------------------------------------------------------
__device__ __forceinline__ float tanh_rcp(float x) {
    float ax = fabsf(x);
    float e2 = __expf(-2.0f * ax);
    float th = (1.0f - e2) * __builtin_amdgcn_rcpf(1.0f + e2);
    return copysignf(th, x);
}

// ---------------------------------------------------------------------------
// Kernel 2: persistent 4-wave blocks, T14 reg-staged async pipeline with raw
// s_barrier (no vmcnt(0) drain -> next tile's global loads stay in flight
// through the barriers and land at the ds_write, hidden under compute).
//   block -> fixed (b, hg, t-range of 256 rows); 16 tiles of 16 rows each.
//   iter: issue next-tile loads -> regs | compute cur tile from LDS | store |
//         s_barrier | ds_write regs->LDS | lgkmcnt(0) | s_barrier.
// ---------------------------------------------------------------------------
__global__ void __launch_bounds__(256)
attn_kernel(const float* __restrict__ q,
            const float* __restrict__ v,
            const float* __restrict__ ksum,
            float* __restrict__ out) {
    __shared__ float sbuf[2 * 16 * ROWSF];    // q tile + v tile, 20992 B

    const int tid   = threadIdx.x;            // 0..255
    const int bid   = blockIdx.x;             // 0..1023
    const int combo = bid >> 4;               // b*4 + hg
    const int tpart = bid & (NPART - 1);
    const int b  = combo >> 2;
    const int hg = combo & 3;

    // staging slot decomposition: 1280 f4 slots = q(0..639) then v(640..1279)
    int sr[5], sc[5], qsel[5];
    #pragma unroll
    for (int i = 0; i < 5; ++i) {
        int idx = tid + 256 * i;
        int qq  = (idx < 640) ? 1 : 0;        // wave-uniform for every i
        int s   = qq ? idx : (idx - 640);
        sr[i] = s / 40;                       // tile row 0..15
        sc[i] = s % 40;                       // f4 col 0..39
        qsel[i] = qq;
    }

    const int row  = tid & 15;
    const int head = tid >> 4;                // 0..15

    // hoist ksum*R into registers (one head per thread)
    const float R = 0.316227766016838f;       // 1/sqrt(10)
    float ksr[10];
    {
        const float* ks = ksum + b * MM + hg * 160 + head * 10;
        #pragma unroll
        for (int d = 0; d < 10; ++d) ksr[d] = ks[d] * R;
    }

    const float4* qb4 = (const float4*)q + (size_t)b * TT * 160 + hg * 40;
    const float4* vb4 = (const float4*)v + (size_t)b * TT * 160 + hg * 40;
    float* ob = out + ((size_t)(b * HH + hg * 16 + head)) * TT + row;

    float4  rs[5];
    float4* s4 = (float4*)sbuf;
    const int tbase = tpart * (NITER * 16);   // first t-row of this block

    // ---- prologue: stage tile 0 ----
    #pragma unroll
    for (int i = 0; i < 5; ++i) {
        const float4* base = qsel[i] ? qb4 : vb4;
        rs[i] = base[(size_t)(tbase + sr[i]) * 160 + sc[i]];
    }
    #pragma unroll
    for (int i = 0; i < 5; ++i)
        s4[(qsel[i] ? 0 : 656) + sr[i] * PAD4 + sc[i]] = rs[i];
    asm volatile("s_waitcnt lgkmcnt(0)" ::: "memory");
    __builtin_amdgcn_s_barrier();
    __builtin_amdgcn_sched_barrier(0);

    for (int it = 0; it < NITER; ++it) {
        const int trow0 = tbase + it * 16;

        // ---- issue next tile's loads (stay in flight through barriers) ----
        if (it + 1 < NITER) {
            const int trn = trow0 + 16;
            #pragma unroll
            for (int i = 0; i < 5; ++i) {
                const float4* base = qsel[i] ? qb4 : vb4;
                rs[i] = base[(size_t)(trn + sr[i]) * 160 + sc[i]];
            }
        }
        __builtin_amdgcn_sched_barrier(0);    // loads must issue before compute

        // ---- compute current tile from LDS ----
        const int fb = row * ROWSF + head * 10;
        float sum = 0.f, dot = 0.f;
        #pragma unroll
        for (int d = 0; d < 10; ++d) {
            float e = __expf(tanh_rcp(sbuf[fb + d] * ksr[d]));
            sum += e;
            dot += e * sbuf[QVOFF + fb + d];
        }
        ob[trow0] = dot * __builtin_amdgcn_rcpf(sum);

        __builtin_amdgcn_sched_barrier(0);
        __builtin_amdgcn_s_barrier();         // all waves done reading sbuf

        if (it + 1 < NITER) {
            // ---- write-late: compiler inserts counted vmcnt for reg deps ----
            #pragma unroll
            for (int i = 0; i < 5; ++i)
                s4[(qsel[i] ? 0 : 656) + sr[i] * PAD4 + sc[i]] = rs[i];
            asm volatile("s_waitcnt lgkmcnt(0)" ::: "memory");
            __builtin_amdgcn_s_barrier();     // tile visible to all waves
            __builtin_amdgcn_sched_barrier(0);
        }
    }
}

// ---------------------------------------------------------------------------
extern "C" void kernel_launch(void* const* d_in, const int* in_sizes, int n_in,
                              void* d_out, int out_size, void* d_ws, size_t ws_size,
                              hipStream_t stream) {
    const float* q = (const float*)d_in[0];
    const float* k = (const float*)d_in[1];
    const float* v = (const float*)d_in[2];
    // d_in[3] = W, d_in[4] = b : dead code (softmax over size-1 axis == 1)
    float* out  = (float*)d_out;
    float* ksum = (float*)d_ws;    // B*M floats = 40 KB

    hipMemsetAsync(d_ws, 0, (size_t)BB * MM * sizeof(float), stream);
    ksum_kernel<<<dim3(10, 128), dim3(256), 0, stream>>>(k, ksum);
    attn_kernel<<<dim3(NBLK), dim3(256), 0, stream>>>(q, v, ksum, out);
}

// Round 8
// 131.311 us; speedup vs baseline: 1.1684x; 1.1684x over previous
//
#include <hip/hip_runtime.h>
#include <stdint.h>

// Problem constants
#define BB 16
#define TT 4096
#define HH 64
#define MM 640     // HH*DD

// attn geometry: block = (b, 4 t-rows, ALL heads) -> contiguous 10KB streams
#define ROWS 4
#define TILE_F4 (ROWS * 160)     // 640 float4 per tensor per tile

// ---------------------------------------------------------------------------
// Kernel 1: ksum[b][m] = sum_t key[b][t][m]  (contiguous 80KB/block streams)
// ---------------------------------------------------------------------------
__global__ void __launch_bounds__(256)
ksum_kernel(const float* __restrict__ key, float* __restrict__ ksum) {
    int g = blockIdx.x * blockDim.x + threadIdx.x;   // b*160 + c
    int b = g / 160;
    int c = g % 160;
    int t0 = blockIdx.y * 32;

    const float4* p = reinterpret_cast<const float4*>(key)
                    + (size_t)b * TT * 160 + (size_t)t0 * 160 + c;

    float4 a0 = make_float4(0.f,0.f,0.f,0.f);
    float4 a1 = make_float4(0.f,0.f,0.f,0.f);
    float4 a2 = make_float4(0.f,0.f,0.f,0.f);
    float4 a3 = make_float4(0.f,0.f,0.f,0.f);
    #pragma unroll
    for (int i = 0; i < 32; i += 4) {
        float4 x0 = p[(size_t)(i + 0) * 160];
        float4 x1 = p[(size_t)(i + 1) * 160];
        float4 x2 = p[(size_t)(i + 2) * 160];
        float4 x3 = p[(size_t)(i + 3) * 160];
        a0.x += x0.x; a0.y += x0.y; a0.z += x0.z; a0.w += x0.w;
        a1.x += x1.x; a1.y += x1.y; a1.z += x1.z; a1.w += x1.w;
        a2.x += x2.x; a2.y += x2.y; a2.z += x2.z; a2.w += x2.w;
        a3.x += x3.x; a3.y += x3.y; a3.z += x3.z; a3.w += x3.w;
    }
    float sx = (a0.x + a1.x) + (a2.x + a3.x);
    float sy = (a0.y + a1.y) + (a2.y + a3.y);
    float sz = (a0.z + a1.z) + (a2.z + a3.z);
    float sw = (a0.w + a1.w) + (a2.w + a3.w);

    float* dst = ksum + b * MM + c * 4;
    atomicAdd(dst + 0, sx);
    atomicAdd(dst + 1, sy);
    atomicAdd(dst + 2, sz);
    atomicAdd(dst + 3, sw);
}

// ---------------------------------------------------------------------------
// Robust tanh via rcp (exp of negative arg only -> never overflows)
// ---------------------------------------------------------------------------
__device__ __forceinline__ float tanh_rcp(float x) {
    float ax = fabsf(x);
    float e2 = __expf(-2.0f * ax);
    float th = (1.0f - e2) * __builtin_amdgcn_rcpf(1.0f + e2);
    return copysignf(th, x);
}

// ---------------------------------------------------------------------------
// Kernel 2: block = (b, t0..t0+3, all 64 heads).
//   stage : q tile (10KB contiguous) + v tile (10KB contiguous) -> LDS,
//           5 float4 per thread, 1KB contiguous per wave-load.
//   compute: thread (row = tid>>6, head = tid&63) -> 1 output.
//   20KB LDS -> 8 blocks/CU -> 32 waves/CU; block-level overlap hides
//   the per-block vmcnt(0)+barrier drain (R4 regime, now with good DRAM
//   locality: every stream is contiguous, full pages consumed).
// ---------------------------------------------------------------------------
__global__ void __launch_bounds__(256)
attn_kernel(const float* __restrict__ q,
            const float* __restrict__ v,
            const float* __restrict__ ksum,
            float* __restrict__ out) {
    __shared__ float4 s4[2 * TILE_F4];    // [ q: 0..639 | v: 640..1279 ]

    const int tid = threadIdx.x;          // 0..255
    const int t0  = blockIdx.x * ROWS;
    const int b   = blockIdx.y;

    const int row  = tid >> 6;            // 0..3 (one wave per row)
    const int head = tid & 63;            // 0..63

    // hoist ksum*R (per-head 40B row; L1/L2-hot across generations)
    const float R = 0.316227766016838f;   // 1/sqrt(10)
    float ksr[10];
    {
        const float* ks = ksum + b * MM + head * 10;
        #pragma unroll
        for (int d = 0; d < 10; ++d) ksr[d] = ks[d] * R;
    }

    // ---- stage: 1280 f4 = q(640) | v(640), fully contiguous streams ----
    const float4* qt = (const float4*)q + ((size_t)b * TT + t0) * 160;
    const float4* vt = (const float4*)v + ((size_t)b * TT + t0) * 160;

    float4 rs[5];
    #pragma unroll
    for (int i = 0; i < 5; ++i) {
        int idx = tid + 256 * i;          // 0..1279
        rs[i] = (idx < 640) ? qt[idx] : vt[idx - 640];
    }
    #pragma unroll
    for (int i = 0; i < 5; ++i)
        s4[tid + 256 * i] = rs[i];
    __syncthreads();

    // ---- compute ----
    const float* qf = reinterpret_cast<const float*>(s4);
    const int base = row * MM + head * 10;

    float sum = 0.f, dot = 0.f;
    #pragma unroll
    for (int d = 0; d < 10; ++d) {
        float e = __expf(tanh_rcp(qf[base + d] * ksr[d]));
        sum += e;
        dot += e * qf[2560 + base + d];   // v tile at float offset 2560
    }
    out[((size_t)(b * HH + head)) * TT + t0 + row]
        = dot * __builtin_amdgcn_rcpf(sum);
}

// ---------------------------------------------------------------------------
extern "C" void kernel_launch(void* const* d_in, const int* in_sizes, int n_in,
                              void* d_out, int out_size, void* d_ws, size_t ws_size,
                              hipStream_t stream) {
    const float* q = (const float*)d_in[0];
    const float* k = (const float*)d_in[1];
    const float* v = (const float*)d_in[2];
    // d_in[3] = W, d_in[4] = b : dead code (softmax over size-1 axis == 1)
    float* out  = (float*)d_out;
    float* ksum = (float*)d_ws;    // B*M floats = 40 KB

    hipMemsetAsync(d_ws, 0, (size_t)BB * MM * sizeof(float), stream);
    ksum_kernel<<<dim3(10, 128), dim3(256), 0, stream>>>(k, ksum);
    attn_kernel<<<dim3(TT / ROWS, BB), dim3(256), 0, stream>>>(q, v, ksum, out);
}

// Round 9
// 116.067 us; speedup vs baseline: 1.3218x; 1.1313x over previous
//
#include <hip/hip_runtime.h>
#include <stdint.h>

// Problem constants
#define BB 16
#define TT 4096
#define HH 64
#define MM 640    // HH*DD

#define TROWS 16          // t-rows per attn tile
#define PADF4 41          // LDS row stride in float4 (656 B)

// ---------------------------------------------------------------------------
// Kernel 1: ksum[b][m] = sum_t key[b][t][m], XCD-chunked block order.
// ---------------------------------------------------------------------------
__global__ void __launch_bounds__(256)
ksum_kernel(const float* __restrict__ key, float* __restrict__ ksum) {
    // chunked XCD swizzle: 1280 blocks -> each XCD gets 160 consecutive swz
    int i   = blockIdx.x;
    int swz = (i & 7) * 160 + (i >> 3);
    int cx  = swz % 10;                  // column chunk (256 (b,c) pairs)
    int ty  = swz / 10;                  // t chunk (32 rows)

    int g = cx * 256 + threadIdx.x;      // b*160 + c
    int b = g / 160;
    int c = g % 160;
    int t0 = ty * 32;

    const float4* p = reinterpret_cast<const float4*>(key)
                    + (size_t)b * TT * 160 + (size_t)t0 * 160 + c;

    float4 a0 = make_float4(0.f,0.f,0.f,0.f);
    float4 a1 = make_float4(0.f,0.f,0.f,0.f);
    float4 a2 = make_float4(0.f,0.f,0.f,0.f);
    float4 a3 = make_float4(0.f,0.f,0.f,0.f);
    #pragma unroll
    for (int j = 0; j < 32; j += 4) {
        float4 x0 = p[(size_t)(j + 0) * 160];
        float4 x1 = p[(size_t)(j + 1) * 160];
        float4 x2 = p[(size_t)(j + 2) * 160];
        float4 x3 = p[(size_t)(j + 3) * 160];
        a0.x += x0.x; a0.y += x0.y; a0.z += x0.z; a0.w += x0.w;
        a1.x += x1.x; a1.y += x1.y; a1.z += x1.z; a1.w += x1.w;
        a2.x += x2.x; a2.y += x2.y; a2.z += x2.z; a2.w += x2.w;
        a3.x += x3.x; a3.y += x3.y; a3.z += x3.z; a3.w += x3.w;
    }
    float sx = (a0.x + a1.x) + (a2.x + a3.x);
    float sy = (a0.y + a1.y) + (a2.y + a3.y);
    float sz = (a0.z + a1.z) + (a2.z + a3.z);
    float sw = (a0.w + a1.w) + (a2.w + a3.w);

    float* dst = ksum + b * MM + c * 4;
    atomicAdd(dst + 0, sx);
    atomicAdd(dst + 1, sy);
    atomicAdd(dst + 2, sz);
    atomicAdd(dst + 3, sw);
}

// ---------------------------------------------------------------------------
// Robust tanh via rcp (exp of negative arg only -> never overflows)
// ---------------------------------------------------------------------------
__device__ __forceinline__ float tanh_rcp(float x) {
    float ax = fabsf(x);
    float e2 = __expf(-2.0f * ax);
    float th = (1.0f - e2) * __builtin_amdgcn_rcpf(1.0f + e2);
    return copysignf(th, x);
}

// ---------------------------------------------------------------------------
// Kernel 2: R4 structure (reg-staged LDS, BLOCK=128, 16 rows x 16 heads,
// coalesced 64B-segment writes) + chunked XCD swizzle with hg FASTEST:
// the 4 hg-sibling blocks of one 40KB row-window are consecutive within an
// XCD -> combined reads cover full contiguous pages in that XCD's L2.
// ---------------------------------------------------------------------------
__global__ void __launch_bounds__(128)
attn_kernel(const float* __restrict__ q,
            const float* __restrict__ v,
            const float* __restrict__ ksum,
            float* __restrict__ out) {
    __shared__ float qs[TROWS * PADF4 * 4];
    __shared__ float vs[TROWS * PADF4 * 4];

    const int tid = threadIdx.x;          // 0..127

    // chunked XCD swizzle: each XCD owns 2048 consecutive swz (= 2 batches)
    int i   = blockIdx.x;                 // 0..16383
    int swz = (i & 7) * 2048 + (i >> 3);
    const int hg = swz & 3;               // hg fastest: siblings co-resident
    const int t0 = ((swz >> 2) & 255) * TROWS;
    const int b  = swz >> 10;

    const float4* qg = reinterpret_cast<const float4*>(q)
                     + ((size_t)(b * TT + t0)) * 160 + hg * 40;
    const float4* vg = reinterpret_cast<const float4*>(v)
                     + ((size_t)(b * TT + t0)) * 160 + hg * 40;

    // ---- stage: 5+5 float4 into regs (back-to-back), then LDS ----
    float4 rq[5], rv[5];
    #pragma unroll
    for (int j = 0; j < 5; ++j) {
        int idx = tid + 128 * j;          // 0..639
        int row = idx / 40;
        int c   = idx % 40;
        rq[j] = qg[(size_t)row * 160 + c];
        rv[j] = vg[(size_t)row * 160 + c];
    }
    float4* qs4 = reinterpret_cast<float4*>(qs);
    float4* vs4 = reinterpret_cast<float4*>(vs);
    #pragma unroll
    for (int j = 0; j < 5; ++j) {
        int idx = tid + 128 * j;
        int row = idx / 40;
        int c   = idx % 40;
        qs4[row * PADF4 + c] = rq[j];
        vs4[row * PADF4 + c] = rv[j];
    }
    __syncthreads();

    // ---- compute: 2 (row, head) outputs per thread ----
    const float R = 0.316227766016838f;   // 1/sqrt(10)
    const int head0 = tid >> 4;           // 0..7 (second head = +8)
    const int row   = tid & 15;

    const float* ks0 = ksum + b * MM + hg * 160 + head0 * 10;
    const float* ks1 = ks0 + 80;
    float2 kk0[5], kk1[5];
    #pragma unroll
    for (int j = 0; j < 5; ++j) {
        kk0[j] = *reinterpret_cast<const float2*>(ks0 + 2 * j);
        kk1[j] = *reinterpret_cast<const float2*>(ks1 + 2 * j);
    }

    #pragma unroll
    for (int o = 0; o < 2; ++o) {
        const int head  = head0 + o * 8;
        const int lbase = row * (PADF4 * 4) + head * 10;
        const float2* kk = o ? kk1 : kk0;
        float sum = 0.f, dot = 0.f;
        #pragma unroll
        for (int j = 0; j < 5; ++j) {
            float e0 = __expf(tanh_rcp(qs[lbase + 2*j]     * kk[j].x * R));
            float e1 = __expf(tanh_rcp(qs[lbase + 2*j + 1] * kk[j].y * R));
            sum += e0 + e1;
            dot += e0 * vs[lbase + 2*j] + e1 * vs[lbase + 2*j + 1];
        }
        out[((size_t)(b * HH + hg * 16 + head)) * TT + t0 + row]
            = dot * __builtin_amdgcn_rcpf(sum);
    }
}

// ---------------------------------------------------------------------------
extern "C" void kernel_launch(void* const* d_in, const int* in_sizes, int n_in,
                              void* d_out, int out_size, void* d_ws, size_t ws_size,
                              hipStream_t stream) {
    const float* q = (const float*)d_in[0];
    const float* k = (const float*)d_in[1];
    const float* v = (const float*)d_in[2];
    // d_in[3] = W, d_in[4] = b : dead code (softmax over size-1 axis == 1)
    float* out  = (float*)d_out;
    float* ksum = (float*)d_ws;    // B*M floats = 40 KB

    hipMemsetAsync(d_ws, 0, (size_t)BB * MM * sizeof(float), stream);
    ksum_kernel<<<dim3(1280), dim3(256), 0, stream>>>(k, ksum);
    attn_kernel<<<dim3(16384), dim3(128), 0, stream>>>(q, v, ksum, out);
}